// Round 6
// baseline (118.278 us; speedup 1.0000x reference)
//
#include <hip/hip_runtime.h>

// Rec1_43748536877661 — diagonal SSM block, MI355X gfx950.
// B=2,S=2048,D=128,N=2048. fp32 in/out, bf16 MFMA compute (tol 2.14e-2).
// R15 = R14 with s_sleep literal-arg fix (builtin requires constant int).
// TWO-PASS projscan + 8-wave outproj.
// R11-R13 post-mortem: three sync/latency theories (serial chain, cross-XCD
// RTT, poll flood) all tested ~null; dur_us ~= fill(44, harness) +
// projscan(~41) + prep/outproj/gaps(~30). This round changes the STRUCTURE:
//  - projscan pass 1: aggregates only (B/dt MFMAs, no y state) -> publish
//    early -> decoupled gather (unchanged machinery) -> pass 2 recomputes
//    projections with tile-init KNOWN, emits y directly. Eliminates the
//    24-VGPR/thread deferred y/coef state, the coefficient stream, and the
//    separate fixup pass; one bf16 rounding instead of sum-of-rounded.
//  - outproj: 8 waves x 8 k-steps (was 4 x 16): halves exposed dependent
//    L2-load->MFMA depth at 1 block/CU.
//  1. prep      pack x,W_B/dt/C,W_out fragment-linear bf16; Aval; zero Sbuf
//  2. projscan  grid(16,64), two-pass, decoupled tagged-atomic lookback
//  3. outproj   y @ W_out^T + b_out -> fp32 out
// Deadlock safety: waiter at row position j targets positions <j whose
// swizzled linear ids are strictly smaller (dispatched earlier; publish is
// unconditional after pass 1) -> acyclic for ANY id->XCD mapping.

#define BB 2
#define SS 2048
#define DDIM 128
#define NDIM 2048
#define TT (BB*SS)        // 4096 tokens
#define NTILE (TT/16)     // 256 t-tiles

typedef short short8 __attribute__((ext_vector_type(8)));
typedef float floatx4 __attribute__((ext_vector_type(4)));

__device__ __forceinline__ unsigned short f2b(float f){
  unsigned u = __float_as_uint(f);
  u += 0x7FFFu + ((u >> 16) & 1u);
  return (unsigned short)(u >> 16);
}
__device__ __forceinline__ unsigned cvt_pk_bf16(float lo, float hi){
  unsigned r;
  asm("v_cvt_pk_bf16_f32 %0, %1, %2" : "=v"(r) : "v"(lo), "v"(hi));
  return r;
}
__device__ __forceinline__ float softplus_f(float v){
  return v > 15.f ? v : __logf(1.f + __expf(v));
}
__device__ __forceinline__ void pack8(const float* __restrict__ s,
                                      unsigned short* __restrict__ d){
  floatx4 v0 = *(const floatx4*)s;
  floatx4 v1 = *(const floatx4*)(s + 4);
  short8 r;
  r[0]=(short)f2b(v0[0]); r[1]=(short)f2b(v0[1]); r[2]=(short)f2b(v0[2]); r[3]=(short)f2b(v0[3]);
  r[4]=(short)f2b(v1[0]); r[5]=(short)f2b(v1[1]); r[6]=(short)f2b(v1[2]); r[7]=(short)f2b(v1[3]);
  *(short8*)d = r;
}

// ---------------- 1. prep ----------------
__global__ void prep_kernel(const float* __restrict__ x,
                            const float* __restrict__ W_B,
                            const float* __restrict__ W_C,
                            const float* __restrict__ W_dt,
                            const float* __restrict__ A_log,
                            const float* __restrict__ W_out,
                            unsigned short* __restrict__ xp,
                            unsigned short* __restrict__ Wp3,
                            unsigned short* __restrict__ Wop,
                            float* __restrict__ Aval,
                            unsigned long long* __restrict__ Sbuf){
  const int gid = blockIdx.x * blockDim.x + threadIdx.x;   // 0..98303
  if (gid < 32768) Sbuf[gid] = 0ull;              // clear (1024 entries x 32 n)
  if (gid < 2048) Aval[gid] = -__expf(A_log[gid]);
  if (gid < 65536){                               // x: 256 t-tiles, K=128
    int g = gid, tile = g >> 8, kk = (g >> 6) & 3, lane = g & 63;
    int q = lane >> 4, m = lane & 15;
    pack8(x + (size_t)(tile*16 + m)*DDIM + kk*32 + q*8, xp + (size_t)g*8);
  }
  if (gid < 98304){                               // W_B/W_dt/W_C: 128 n-tiles each
    int mat = gid >> 15, g = gid & 32767;
    const float* W = (mat == 0) ? W_B : (mat == 1 ? W_dt : W_C);
    int tile = g >> 8, kk = (g >> 6) & 3, lane = g & 63;
    int q = lane >> 4, m = lane & 15;
    pack8(W + (size_t)(tile*16 + m)*DDIM + kk*32 + q*8,
          Wp3 + (size_t)mat*262144 + (size_t)g*8);
  }
  if (gid < 32768){                               // W_out: 8 d-tiles, K=2048
    int g = gid, tile = g >> 12, kk = (g >> 6) & 63, lane = g & 63;
    int q = lane >> 4, m = lane & 15;
    pack8(W_out + (size_t)(tile*16 + m)*NDIM + kk*32 + q*8, Wop + (size_t)g*8);
  }
}

// ---------------- 2. projscan, two-pass, XCD-local decoupled lookback -------
// grid (16, 64), block 256. Physical id p = by*16+bx is swizzled:
//   xcd=p&7, slot=p>>3, rr=slot&15, j=slot>>4, row=xcd*16+rr
//   by=row>>1, bx=(row&1)*8+j   (j = position within the 8-block chain row)
// (256,2): VGPR budget 256 -> natural (no forced cap; R10 spill lesson).
__global__ __launch_bounds__(256, 2) void projscan_kernel(
    const unsigned short* __restrict__ xp,
    const unsigned short* __restrict__ Wp3,
    const float* __restrict__ b_B,
    const float* __restrict__ b_dt,
    const float* __restrict__ b_C,
    const float* __restrict__ Aval,
    unsigned long long* __restrict__ Sbuf,   // [64*16][32] packed (P|H)
    unsigned short* __restrict__ ybp){
  __shared__ unsigned short sW[3*4096];      // 24 KB packed weights (both passes)
  __shared__ unsigned short sYT[4][640];     // per-wave transpose tile (pass 2)
  __shared__ float sPw[4][32], sHw[4][32];   // per-wave chain totals
  __shared__ float sIw[4][32];               // per-wave init states
  const int tid  = threadIdx.x;
  const int lane = tid & 63;
  const int wv   = tid >> 6;
  const int m    = lane & 15;
  const int q    = lane >> 4;
  // --- XCD-local row swizzle ---
  const int p    = blockIdx.y * 16 + blockIdx.x;  // dispatch-linear id
  const int xcd  = p & 7;
  const int slot = p >> 3;                        // 0..127
  const int rr   = slot & 15;
  const int j    = slot >> 4;                     // 0..7 position in row
  const int row  = xcd*16 + rr;                   // 0..127
  const int by   = row >> 1;                      // n-slice 0..63
  const int bx   = (row & 1)*8 + j;               // t-chunk 0..15
  const int n0   = by*32;

  // stage packed weights: 3 mats x 2 n-tiles x 2048 ushort
  for (int i = tid; i < 1536; i += 256){
    int mat = i >> 9, rem = i & 511;
    *(short8*)(sW + mat*4096 + rem*8) =
        *(const short8*)(Wp3 + (size_t)mat*262144 + (size_t)by*4096 + rem*8);
  }
  __syncthreads();

  // per-nt biases (n = n0 + nt*16 + m)
  float bBv[2], bDv[2], bCv[2], Avv[2];
#pragma unroll
  for (int nt = 0; nt < 2; ++nt){
    const int n = n0 + nt*16 + m;
    bBv[nt] = b_B[n]; bDv[nt] = b_dt[n]; bCv[nt] = b_C[n]; Avv[nt] = Aval[n];
  }

  // ==== PASS 1: aggregates only (no y, no deferred state) ====
  float pa_run[2] = {1.f, 1.f}, ha_run[2] = {0.f, 0.f};
#pragma unroll
  for (int i = 0; i < 4; ++i){
    const int tile = bx*16 + wv*4 + i;
    short8 xf[4];
#pragma unroll
    for (int kk = 0; kk < 4; ++kk)
      xf[kk] = *(const short8*)(xp + (size_t)tile*2048 + kk*512 + lane*8);

    floatx4 aB[2], aD[2];
#pragma unroll
    for (int nt = 0; nt < 2; ++nt){
      aB[nt] = (floatx4){0.f,0.f,0.f,0.f};
      aD[nt] = (floatx4){0.f,0.f,0.f,0.f};
    }
#pragma unroll
    for (int nt = 0; nt < 2; ++nt)
#pragma unroll
      for (int kk = 0; kk < 4; ++kk){
        short8 wB = *(const short8*)(sW +         nt*2048 + kk*512 + lane*8);
        short8 wD = *(const short8*)(sW + 4096 +  nt*2048 + kk*512 + lane*8);
        aB[nt] = __builtin_amdgcn_mfma_f32_16x16x32_bf16(xf[kk], wB, aB[nt], 0, 0, 0);
        aD[nt] = __builtin_amdgcn_mfma_f32_16x16x32_bf16(xf[kk], wD, aD[nt], 0, 0, 0);
      }

#pragma unroll
    for (int nt = 0; nt < 2; ++nt){
      float P, H;
      {
        float Ar[4], Br[4];
#pragma unroll
        for (int r = 0; r < 4; ++r){
          float dtv = softplus_f(aD[nt][r] + bDv[nt]);
          Ar[r] = __expf(dtv * Avv[nt]);
          Br[r] = dtv * (aB[nt][r] + bBv[nt]);
        }
        P = Ar[0]; H = Br[0];
#pragma unroll
        for (int r = 1; r < 4; ++r){ H = Ar[r]*H + Br[r]; P *= Ar[r]; }
      }
      // inclusive scan across q (2 steps)
      float pp = __shfl(P, (lane - 16) & 63, 64);
      float hh = __shfl(H, (lane - 16) & 63, 64);
      if (q >= 1){ H = P*hh + H; P *= pp; }
      pp = __shfl(P, (lane - 32) & 63, 64);
      hh = __shfl(H, (lane - 32) & 63, 64);
      if (q >= 2){ H = P*hh + H; P *= pp; }
      // tile totals broadcast (q==3 inclusive)
      float pb = __shfl(P, m + 48, 64);
      float hb = __shfl(H, m + 48, 64);
      ha_run[nt] = pb*ha_run[nt] + hb;
      pa_run[nt] *= pb;
    }
  }
  // publish wave totals per n (identical across q; q==0 writes)
  if (q == 0){
#pragma unroll
    for (int nt = 0; nt < 2; ++nt){
      sPw[wv][nt*16 + m] = pa_run[nt];
      sHw[wv][nt*16 + m] = ha_run[nt];
    }
  }
  __syncthreads();

  // ---- publish LOCAL aggregate, decoupled lookback (threads 0..31) ----
  if (tid < 32){
    float Pw[4], Hw[4];
#pragma unroll
    for (int w2 = 0; w2 < 4; ++w2){ Pw[w2] = sPw[w2][tid]; Hw[w2] = sHw[w2][tid]; }
    // block-local aggregate over the 4 waves
    float pb = 1.f, hb = 0.f;
#pragma unroll
    for (int w2 = 0; w2 < 4; ++w2){ hb = Pw[w2]*hb + Hw[w2]; pb *= Pw[w2]; }
    // single-word publish: [P|H]; validity = P bits != 0 (P>0, clamped)
    float pbc = fmaxf(pb, 1e-30f);
    __hip_atomic_store(Sbuf + (size_t)(by*16 + bx)*32 + tid,
        ((unsigned long long)__float_as_uint(pbc) << 32) |
         (unsigned long long)__float_as_uint(hb),
        __ATOMIC_RELAXED, __HIP_MEMORY_SCOPE_AGENT);
    // gather ALL predecessors' locals concurrently (retry-mask + backoff)
    float S = 0.f;
    const int cnt = bx & 7;                // # predecessors within batch row
    if (cnt){
      const int j0 = bx & ~7;
      unsigned long long v0=0,v1=0,v2=0,v3=0,v4=0,v5=0,v6=0;
      unsigned got = 0;
      int spin = 0;
      const unsigned all = (1u << cnt) - 1u;
      const unsigned long long* base = Sbuf + (size_t)(by*16 + j0)*32 + tid;
      for (;;){
#define LOOKBACK(J, V)                                                          \
        if (J < cnt && !(got & (1u << J))){                                     \
          unsigned long long a = __hip_atomic_load(base + (size_t)J*32,         \
              __ATOMIC_RELAXED, __HIP_MEMORY_SCOPE_AGENT);                      \
          if ((unsigned)(a >> 32) != 0u){ V = a; got |= 1u << J; }              \
        }
        LOOKBACK(0, v0) LOOKBACK(1, v1) LOOKBACK(2, v2) LOOKBACK(3, v3)
        LOOKBACK(4, v4) LOOKBACK(5, v5) LOOKBACK(6, v6)
#undef LOOKBACK
        if (got == all) break;
        if (spin < 4) __builtin_amdgcn_s_sleep(2);
        else          __builtin_amdgcn_s_sleep(8);
        ++spin;
      }
      // ordered composition j0..bx-1: S = P_j*S + H_j
#define COMPOSE(J, V)                                                           \
      if (J < cnt) S = __uint_as_float((unsigned)(V >> 32))*S +                 \
                       __uint_as_float((unsigned)V);
      COMPOSE(0, v0) COMPOSE(1, v1) COMPOSE(2, v2) COMPOSE(3, v3)
      COMPOSE(4, v4) COMPOSE(5, v5) COMPOSE(6, v6)
#undef COMPOSE
    }
    // per-wave init states
    float s = S;
#pragma unroll
    for (int w2 = 0; w2 < 4; ++w2){
      sIw[w2][tid] = s;
      s = Pw[w2]*s + Hw[w2];
    }
  }
  __syncthreads();

  // ==== PASS 2: recompute with known init, emit y directly ====
  float it_run[2];
#pragma unroll
  for (int nt = 0; nt < 2; ++nt) it_run[nt] = sIw[wv][nt*16 + m];

#pragma unroll
  for (int i = 0; i < 4; ++i){
    const int tile = bx*16 + wv*4 + i;
    short8 xf[4];
#pragma unroll
    for (int kk = 0; kk < 4; ++kk)
      xf[kk] = *(const short8*)(xp + (size_t)tile*2048 + kk*512 + lane*8);

    floatx4 acc[3][2];
#pragma unroll
    for (int mat = 0; mat < 3; ++mat)
#pragma unroll
      for (int nt = 0; nt < 2; ++nt)
        acc[mat][nt] = (floatx4){0.f,0.f,0.f,0.f};
#pragma unroll
    for (int nt = 0; nt < 2; ++nt)
#pragma unroll
      for (int kk = 0; kk < 4; ++kk){
        short8 wB = *(const short8*)(sW +         nt*2048 + kk*512 + lane*8);
        short8 wD = *(const short8*)(sW + 4096 +  nt*2048 + kk*512 + lane*8);
        short8 wC = *(const short8*)(sW + 8192 +  nt*2048 + kk*512 + lane*8);
        acc[0][nt] = __builtin_amdgcn_mfma_f32_16x16x32_bf16(xf[kk], wB, acc[0][nt], 0, 0, 0);
        acc[1][nt] = __builtin_amdgcn_mfma_f32_16x16x32_bf16(xf[kk], wD, acc[1][nt], 0, 0, 0);
        acc[2][nt] = __builtin_amdgcn_mfma_f32_16x16x32_bf16(xf[kk], wC, acc[2][nt], 0, 0, 0);
      }

#pragma unroll
    for (int nt = 0; nt < 2; ++nt){
      float Ar[4], Br[4], Cc[4];
#pragma unroll
      for (int r = 0; r < 4; ++r){
        float dtv = softplus_f(acc[1][nt][r] + bDv[nt]);
        Ar[r] = __expf(dtv * Avv[nt]);
        Br[r] = dtv * (acc[0][nt][r] + bBv[nt]);
        Cc[r] = acc[2][nt][r] + bCv[nt];
      }
      // compose lane's 4-token segment
      float P = Ar[0], H = Br[0];
#pragma unroll
      for (int r = 1; r < 4; ++r){ H = Ar[r]*H + Br[r]; P *= Ar[r]; }
      // inclusive scan across q (2 steps)
      float pp = __shfl(P, (lane - 16) & 63, 64);
      float hh = __shfl(H, (lane - 16) & 63, 64);
      if (q >= 1){ H = P*hh + H; P *= pp; }
      pp = __shfl(P, (lane - 32) & 63, 64);
      hh = __shfl(H, (lane - 32) & 63, 64);
      if (q >= 2){ H = P*hh + H; P *= pp; }
      // exclusive prefix for this q
      float pe = __shfl(P, (lane - 16) & 63, 64);
      float he = __shfl(H, (lane - 16) & 63, 64);
      if (q == 0){ pe = 1.f; he = 0.f; }
      // tile totals broadcast (q==3 inclusive)
      float pb = __shfl(P, m + 48, 64);
      float hb = __shfl(H, m + 48, 64);

      // exact h from known tile init; y emitted directly (one rounding)
      float h = pe*it_run[nt] + he;
      float ys[4];
#pragma unroll
      for (int r = 0; r < 4; ++r){
        h = Ar[r]*h + Br[r];
        ys[r] = Cc[r]*h;
      }
      unsigned y01 = cvt_pk_bf16(ys[0], ys[1]);
      unsigned y23 = cvt_pk_bf16(ys[2], ys[3]);
      sYT[wv][(q*4 + 0)*40 + nt*16 + m] = (unsigned short)(y01);
      sYT[wv][(q*4 + 1)*40 + nt*16 + m] = (unsigned short)(y01 >> 16);
      sYT[wv][(q*4 + 2)*40 + nt*16 + m] = (unsigned short)(y23);
      sYT[wv][(q*4 + 3)*40 + nt*16 + m] = (unsigned short)(y23 >> 16);

      it_run[nt] = pb*it_run[nt] + hb;
    }
    short8 yv = *(const short8*)&sYT[wv][m*40 + q*8];
    *(short8*)(ybp + (size_t)tile*32768 + (size_t)by*512 + (size_t)lane*8) = yv;
  }
}

// ---------------- 3. output projection ----------------
// grid NTILE=256, block 512 (8 waves). Wave wv: kk in [wv*8, wv*8+8),
// all 8 d-tiles -> half the serial dependent-load->MFMA depth of the 4-wave
// version, same traffic. red: 8 partials x 2048 = 64 KB LDS.
__global__ __launch_bounds__(512, 1) void outproj_kernel(
    const unsigned short* __restrict__ ybp,
    const unsigned short* __restrict__ Wop,
    const float* __restrict__ b_out,
    float* __restrict__ out){
  __shared__ float red[8*2048];
  const int tid  = threadIdx.x;
  const int lane = tid & 63;
  const int wv   = tid >> 6;             // 0..7
  const int m    = lane & 15;
  const int q    = lane >> 4;
  const int tile = blockIdx.x;

  floatx4 acc[8];
#pragma unroll
  for (int dt = 0; dt < 8; ++dt) acc[dt] = (floatx4){0.f,0.f,0.f,0.f};

  const unsigned short* aP = ybp + (size_t)tile*32768 + lane*8;
  const unsigned short* bP = Wop + (size_t)lane*8;
#pragma unroll
  for (int kk = wv*8; kk < wv*8 + 8; ++kk){
    short8 af = *(const short8*)(aP + (size_t)kk*512);
#pragma unroll
    for (int dt = 0; dt < 8; ++dt){
      short8 bf = *(const short8*)(bP + (size_t)dt*32768 + (size_t)kk*512);
      acc[dt] = __builtin_amdgcn_mfma_f32_16x16x32_bf16(af, bf, acc[dt], 0, 0, 0);
    }
  }
#pragma unroll
  for (int dt = 0; dt < 8; ++dt)
#pragma unroll
    for (int r = 0; r < 4; ++r)
      red[wv*2048 + (q*4 + r)*128 + dt*16 + m] = acc[dt][r];
  __syncthreads();
#pragma unroll
  for (int i = 0; i < 4; ++i){
    int idx = i*512 + tid;                        // 0..2047 = tl*128 + d
    float s = red[idx]          + red[2048 + idx] + red[4096 + idx] + red[6144 + idx]
            + red[8192 + idx]   + red[10240 + idx] + red[12288 + idx] + red[14336 + idx];
    int tl = idx >> 7, d = idx & 127;
    out[(size_t)(tile*16 + tl)*DDIM + d] = s + b_out[d];
  }
}

extern "C" void kernel_launch(void* const* d_in, const int* in_sizes, int n_in,
                              void* d_out, int out_size, void* d_ws, size_t ws_size,
                              hipStream_t stream) {
  const float* x     = (const float*)d_in[0];
  const float* W_B   = (const float*)d_in[1];
  const float* b_B   = (const float*)d_in[2];
  const float* W_C   = (const float*)d_in[3];
  const float* b_C   = (const float*)d_in[4];
  const float* W_dt  = (const float*)d_in[5];
  const float* b_dt  = (const float*)d_in[6];
  const float* A_log = (const float*)d_in[7];
  const float* W_out = (const float*)d_in[8];
  const float* b_out = (const float*)d_in[9];
  float* out = (float*)d_out;

  char* w = (char*)d_ws;
  unsigned short* xp    = (unsigned short*)(w + 0x0000000);  // 1 MB
  unsigned short* Wp3   = (unsigned short*)(w + 0x0100000);  // 1.5 MB
  unsigned short* Wop   = (unsigned short*)(w + 0x0280000);  // 0.5 MB
  float*          Aval  = (float*)         (w + 0x0300000);  // 8 KB
  unsigned short* ybp   = (unsigned short*)(w + 0x0310000);  // 16 MB
  unsigned long long* Sbuf = (unsigned long long*)(w + 0x1310000); // 256 KB
  // total ~19.7 MB

  prep_kernel<<<384, 256, 0, stream>>>(
      x, W_B, W_C, W_dt, A_log, W_out, xp, Wp3, Wop, Aval, Sbuf);

  projscan_kernel<<<dim3(16, 64), 256, 0, stream>>>(
      xp, Wp3, b_B, b_dt, b_C, Aval, Sbuf, ybp);

  outproj_kernel<<<NTILE, 512, 0, stream>>>(ybp, Wop, b_out, out);
}